// Round 1
// baseline (106.918 us; speedup 1.0000x reference)
//
#include <hip/hip_runtime.h>

#define PATCH_LENGTH 128
#define PATCH_STRIDE 64
#define WINDOW_SIZE 16

// ---------------- Kernel 1: adj = sigmoid(edge_weights) * band_mask -> d_ws ----------------
__global__ void adj_compute_kernel(const float* __restrict__ ew, float* __restrict__ adj) {
    int idx = blockIdx.x * blockDim.x + threadIdx.x;
    if (idx < PATCH_LENGTH * PATCH_LENGTH) {
        int i = idx >> 7;
        int j = idx & 127;
        int d = i - j; if (d < 0) d = -d;
        float s = 1.0f / (1.0f + expf(-ew[idx]));
        adj[idx] = (d > 0 && d <= WINDOW_SIZE) ? s : 0.0f;
    }
}

// ---------------- Kernel 2: patches[p, t, {0,1}] = {I[p*64+t], Q[p*64+t]} ----------------
__global__ void patches_kernel(const float* __restrict__ I, const float* __restrict__ Q,
                               float2* __restrict__ out, int total) {
    int idx = blockIdx.x * blockDim.x + threadIdx.x;
    if (idx < total) {
        int p = idx >> 7;      // patch index
        int t = idx & 127;     // within-patch index
        int src = p * PATCH_STRIDE + t;
        out[idx] = make_float2(I[src], Q[src]);
    }
}

// ---------------- Kernel 3: broadcast adj to [P,128,128], one block per patch ----------------
__global__ void adjs_broadcast_kernel(const float4* __restrict__ adj4, float4* __restrict__ out) {
    const int per_patch4 = PATCH_LENGTH * PATCH_LENGTH / 4;  // 4096 float4 = 64 KB
    float4* dst = out + (size_t)blockIdx.x * per_patch4;
#pragma unroll
    for (int k = 0; k < per_patch4 / 256; ++k) {
        int idx = k * 256 + threadIdx.x;
        dst[idx] = adj4[idx];
    }
}

// ---------------- Fallback: no-workspace variant (adj computed per-block into LDS) ----------------
__global__ void adjs_broadcast_lds_kernel(const float* __restrict__ ew, float4* __restrict__ out) {
    __shared__ float adj[PATCH_LENGTH * PATCH_LENGTH];
    for (int k = threadIdx.x; k < PATCH_LENGTH * PATCH_LENGTH; k += blockDim.x) {
        int i = k >> 7, j = k & 127;
        int d = i - j; if (d < 0) d = -d;
        float s = 1.0f / (1.0f + expf(-ew[k]));
        adj[k] = (d > 0 && d <= WINDOW_SIZE) ? s : 0.0f;
    }
    __syncthreads();
    const int per_patch4 = PATCH_LENGTH * PATCH_LENGTH / 4;
    float4* dst = out + (size_t)blockIdx.x * per_patch4;
    const float4* a4 = reinterpret_cast<const float4*>(adj);
#pragma unroll
    for (int k = 0; k < per_patch4 / 256; ++k) {
        int idx = k * 256 + threadIdx.x;
        dst[idx] = a4[idx];
    }
}

extern "C" void kernel_launch(void* const* d_in, const int* in_sizes, int n_in,
                              void* d_out, int out_size, void* d_ws, size_t ws_size,
                              hipStream_t stream) {
    const float* I  = (const float*)d_in[0];
    const float* Q  = (const float*)d_in[1];
    const float* ew = (const float*)d_in[2];
    float* out = (float*)d_out;

    const int n = in_sizes[0];
    const int P = (n - PATCH_LENGTH) / PATCH_STRIDE + 1;  // 7811 for L=500000

    // patches occupy P*128*2 floats at the front of d_out
    const int totalPT = P * PATCH_LENGTH;
    patches_kernel<<<(totalPT + 255) / 256, 256, 0, stream>>>(I, Q, (float2*)out, totalPT);

    float* adj_out = out + (size_t)P * PATCH_LENGTH * 2;  // P*1024 bytes offset -> 16B aligned

    if (ws_size >= (size_t)PATCH_LENGTH * PATCH_LENGTH * sizeof(float)) {
        float* adj = (float*)d_ws;
        adj_compute_kernel<<<(PATCH_LENGTH * PATCH_LENGTH + 255) / 256, 256, 0, stream>>>(ew, adj);
        adjs_broadcast_kernel<<<P, 256, 0, stream>>>((const float4*)adj, (float4*)adj_out);
    } else {
        adjs_broadcast_lds_kernel<<<P, 256, 0, stream>>>(ew, (float4*)adj_out);
    }
}